// Round 1
// baseline (504.983 us; speedup 1.0000x reference)
//
#include <hip/hip_runtime.h>

// Self-attention: x(4,2048,1024) fp32; W_Q/K/V/O (1024,1024) fp32.
// out = softmax_causal((xWq^T)(xWk^T)^T/sqrt(64)) (xWv^T) Wo^T, fp32.
// Strategy: cast everything to bf16, MFMA GEMMs + flash attention, fp32 accum.

#define B_  4
#define S_  2048
#define D_  1024
#define H_  16
#define HD_ 64
#define M_  (B_*S_)   // 8192 tokens

typedef __attribute__((ext_vector_type(8))) short bf16x8;
typedef __attribute__((ext_vector_type(4))) float f32x4;

__device__ __forceinline__ unsigned short f2b(float f) {
  unsigned u = __builtin_bit_cast(unsigned, f);
  unsigned r = (u + 0x7FFFu + ((u >> 16) & 1u)) >> 16;  // RNE
  return (unsigned short)r;
}

// ---------------- fp32 -> bf16 conversion (vectorized) ----------------
__global__ __launch_bounds__(256) void cvt4_kernel(const float4* __restrict__ in,
                                                   ushort4* __restrict__ out, int n4) {
  int i = blockIdx.x * 256 + threadIdx.x;
  if (i >= n4) return;
  float4 v = in[i];
  ushort4 o;
  o.x = f2b(v.x); o.y = f2b(v.y); o.z = f2b(v.z); o.w = f2b(v.w);
  out[i] = o;
}

// ---------------- GEMM: C[M,N] = A[M,K] * Bw[N,K]^T (bf16 in, K=N=1024) -----
// MODE 0: grid.z selects (Bw, Out) among Q/K/V; bf16 output remapped to
//         [b][h][s][hd] layout. MODE 1: fp32 output, row-major [m][n].
template<int MODE>
__global__ __launch_bounds__(256) void gemm_bt(
    const unsigned short* __restrict__ A,
    const unsigned short* __restrict__ B0,
    const unsigned short* __restrict__ B1,
    const unsigned short* __restrict__ B2,
    unsigned short* __restrict__ O0,
    unsigned short* __restrict__ O1,
    unsigned short* __restrict__ O2,
    float* __restrict__ OF)
{
  const int tid  = threadIdx.x;
  const int lane = tid & 63;
  const int w    = tid >> 6;          // wave 0..3
  const int wm   = w >> 1, wn = w & 1;
  const int r16  = lane & 15, g = lane >> 4;
  const int bm = blockIdx.x, bn = blockIdx.y;

  const unsigned short* Bw = B0;
  unsigned short* Ob = O0;
  if (MODE == 0) {
    if (blockIdx.z == 1)      { Bw = B1; Ob = O1; }
    else if (blockIdx.z == 2) { Bw = B2; Ob = O2; }
  }

  __shared__ unsigned short As[128][40];   // 32 K-cols, pad->40 (80B, 16B-aligned rows)
  __shared__ unsigned short Bs[128][40];

  f32x4 acc[4][4] = {};
  const int arow = bm * 128;
  const int brow = bn * 128;

  for (int k0 = 0; k0 < 1024; k0 += 32) {
    #pragma unroll
    for (int t = 0; t < 2; ++t) {        // 256 thr * 2 * 16B = full 128x32 tile
      int cc  = tid + t * 256;
      int row = cc >> 2, col = (cc & 3) * 8;
      *(uint4*)(&As[row][col]) = *(const uint4*)(&A [(size_t)(arow + row) * 1024 + k0 + col]);
      *(uint4*)(&Bs[row][col]) = *(const uint4*)(&Bw[(size_t)(brow + row) * 1024 + k0 + col]);
    }
    __syncthreads();
    bf16x8 af[4], bfr[4];
    #pragma unroll
    for (int i = 0; i < 4; ++i)
      af[i]  = *(const bf16x8*)(&As[wm*64 + i*16 + r16][g*8]);
    #pragma unroll
    for (int i = 0; i < 4; ++i)
      bfr[i] = *(const bf16x8*)(&Bs[wn*64 + i*16 + r16][g*8]);
    #pragma unroll
    for (int i = 0; i < 4; ++i)
      #pragma unroll
      for (int j = 0; j < 4; ++j)
        acc[i][j] = __builtin_amdgcn_mfma_f32_16x16x32_bf16(af[i], bfr[j], acc[i][j], 0, 0, 0);
    __syncthreads();
  }

  // epilogue: D layout col=lane&15, row=(lane>>4)*4+r  [HW-verified m89]
  #pragma unroll
  for (int i = 0; i < 4; ++i) {
    #pragma unroll
    for (int j = 0; j < 4; ++j) {
      #pragma unroll
      for (int r = 0; r < 4; ++r) {
        int m = bm*128 + wm*64 + i*16 + g*4 + r;
        int n = bn*128 + wn*64 + j*16 + r16;
        float v = acc[i][j][r];
        if (MODE == 0) {
          int b = m >> 11, s = m & 2047;
          int h = n >> 6,  hd = n & 63;
          Ob[((((size_t)b*H_ + h)*S_) + s)*HD_ + hd] = f2b(v);
        } else {
          OF[(size_t)m * 1024 + n] = v;
        }
      }
    }
  }
}

// ---------------- flash attention, causal -------------------------------
// Q/K/V: [b*h][2048][64] bf16. Each wave owns a 16-row Q tile; 32-col KV steps.
// No __syncthreads (waves have divergent trip counts) — P transpose uses
// wave-private LDS (compiler orders same-wave LDS RAW).
__global__ __launch_bounds__(256) void attn_fwd(
    const unsigned short* __restrict__ Q,
    const unsigned short* __restrict__ K,
    const unsigned short* __restrict__ V,
    unsigned short* __restrict__ C)
{
  const int tid  = threadIdx.x;
  const int lane = tid & 63;
  const int w    = tid >> 6;
  const int r16  = lane & 15, g = lane >> 4;
  const int bh   = blockIdx.y;
  const int bb   = bh >> 4, hh = bh & 15;
  const int qt   = blockIdx.x * 4 + w;
  const int q0   = qt * 16;
  const unsigned short* Qh = Q + (size_t)bh * S_ * HD_;
  const unsigned short* Kh = K + (size_t)bh * S_ * HD_;
  const unsigned short* Vh = V + (size_t)bh * S_ * HD_;
  __shared__ unsigned short Pl[4][16][40];   // per-wave 16x32 P tile, 16B-aligned rows

  bf16x8 qf[2];
  #pragma unroll
  for (int dh = 0; dh < 2; ++dh)
    qf[dh] = *(const bf16x8*)(&Qh[(size_t)(q0 + r16) * HD_ + dh*32 + g*8]);

  f32x4 o[4] = {};
  float mrow[4], lrow[4];
  #pragma unroll
  for (int r = 0; r < 4; ++r) { mrow[r] = -1e30f; lrow[r] = 0.f; }

  const int nk = (q0 + 15) / 32 + 1;
  for (int kt = 0; kt < nk; ++kt) {
    const int kb = kt * 32;
    // ---- scores: S = Q K^T  (two 16-col tiles) ----
    f32x4 sc[2];
    #pragma unroll
    for (int c = 0; c < 2; ++c) {
      f32x4 s = {};
      #pragma unroll
      for (int dh = 0; dh < 2; ++dh) {
        bf16x8 kf = *(const bf16x8*)(&Kh[(size_t)(kb + c*16 + r16) * HD_ + dh*32 + g*8]);
        s = __builtin_amdgcn_mfma_f32_16x16x32_bf16(qf[dh], kf, s, 0, 0, 0);
      }
      sc[c] = s;
    }
    // ---- online softmax (rows split: this lane owns rows g*4+r) ----
    #pragma unroll
    for (int r = 0; r < 4; ++r) {
      const int qrow = q0 + g*4 + r;
      float v0 = sc[0][r] * 0.125f;
      float v1 = sc[1][r] * 0.125f;
      if (kb + r16 > qrow)      v0 = -1e30f;
      if (kb + 16 + r16 > qrow) v1 = -1e30f;
      float t = fmaxf(v0, v1);
      #pragma unroll
      for (int off = 1; off < 16; off <<= 1) t = fmaxf(t, __shfl_xor(t, off));
      float mnew = fmaxf(mrow[r], t);
      float resc = __expf(mrow[r] - mnew);
      mrow[r] = mnew;
      float p0 = __expf(v0 - mnew);
      float p1 = __expf(v1 - mnew);
      float ts = p0 + p1;
      #pragma unroll
      for (int off = 1; off < 16; off <<= 1) ts += __shfl_xor(ts, off);
      lrow[r] = lrow[r] * resc + ts;
      #pragma unroll
      for (int dn = 0; dn < 4; ++dn) o[dn][r] *= resc;
      Pl[w][g*4 + r][r16]      = f2b(p0);
      Pl[w][g*4 + r][16 + r16] = f2b(p1);
    }
    // ---- PV: ctx += P(16x32) V(32x64) ----
    bf16x8 pf = *(const bf16x8*)(&Pl[w][r16][g*8]);
    #pragma unroll
    for (int dn = 0; dn < 4; ++dn) {
      bf16x8 vf;
      #pragma unroll
      for (int j = 0; j < 8; ++j)
        vf[j] = *(const short*)(&Vh[(size_t)(kb + g*8 + j) * HD_ + dn*16 + r16]);
      o[dn] = __builtin_amdgcn_mfma_f32_16x16x32_bf16(pf, vf, o[dn], 0, 0, 0);
    }
  }
  // ---- write ctx merged-head layout [b][s][1024] ----
  #pragma unroll
  for (int dn = 0; dn < 4; ++dn) {
    #pragma unroll
    for (int r = 0; r < 4; ++r) {
      int tok = bb * S_ + q0 + g*4 + r;
      C[(size_t)tok * D_ + hh*HD_ + dn*16 + r16] = f2b(o[dn][r] / lrow[r]);
    }
  }
}

// ---------------- launch ------------------------------------------------
extern "C" void kernel_launch(void* const* d_in, const int* in_sizes, int n_in,
                              void* d_out, int out_size, void* d_ws, size_t ws_size,
                              hipStream_t stream) {
  const float* x  = (const float*)d_in[0];
  const float* Wq = (const float*)d_in[1];
  const float* Wk = (const float*)d_in[2];
  const float* Wv = (const float*)d_in[3];
  const float* Wo = (const float*)d_in[4];

  char* ws = (char*)d_ws;
  unsigned short* xb  = (unsigned short*)(ws);              // 16 MiB
  unsigned short* Wqb = (unsigned short*)(ws + 16777216);   // 2 MiB each
  unsigned short* Wkb = (unsigned short*)(ws + 18874368);
  unsigned short* Wvb = (unsigned short*)(ws + 20971520);
  unsigned short* Wob = (unsigned short*)(ws + 23068672);
  unsigned short* Qb  = (unsigned short*)(ws + 25165824);   // 16 MiB each, [b][h][s][hd]
  unsigned short* Kb  = (unsigned short*)(ws + 41943040);
  unsigned short* Vb  = (unsigned short*)(ws + 58720256);
  unsigned short* Cb  = (unsigned short*)(ws + 75497472);   // ctx [b][s][1024]

  cvt4_kernel<<<8192, 256, 0, stream>>>((const float4*)x,  (ushort4*)xb,  2097152);
  cvt4_kernel<<<1024, 256, 0, stream>>>((const float4*)Wq, (ushort4*)Wqb, 262144);
  cvt4_kernel<<<1024, 256, 0, stream>>>((const float4*)Wk, (ushort4*)Wkb, 262144);
  cvt4_kernel<<<1024, 256, 0, stream>>>((const float4*)Wv, (ushort4*)Wvb, 262144);
  cvt4_kernel<<<1024, 256, 0, stream>>>((const float4*)Wo, (ushort4*)Wob, 262144);

  gemm_bt<0><<<dim3(64, 8, 3), 256, 0, stream>>>(xb, Wqb, Wkb, Wvb, Qb, Kb, Vb, nullptr);
  attn_fwd<<<dim3(32, 64), 256, 0, stream>>>(Qb, Kb, Vb, Cb);
  gemm_bt<1><<<dim3(64, 8, 1), 256, 0, stream>>>(Cb, Wob, nullptr, nullptr,
                                                 nullptr, nullptr, nullptr, (float*)d_out);
}

// Round 2
// 397.747 us; speedup vs baseline: 1.2696x; 1.2696x over previous
//
#include <hip/hip_runtime.h>

// Self-attention: x(4,2048,1024) fp32; W_Q/K/V/O (1024,1024) fp32.
// bf16 MFMA GEMMs + block-cooperative flash attention with pre-transposed V.

#define B_  4
#define S_  2048
#define D_  1024
#define H_  16
#define HD_ 64

typedef __attribute__((ext_vector_type(8))) short bf16x8;
typedef __attribute__((ext_vector_type(4))) float f32x4;

__device__ __forceinline__ unsigned short f2b(float f) {
  unsigned u = __builtin_bit_cast(unsigned, f);
  unsigned r = (u + 0x7FFFu + ((u >> 16) & 1u)) >> 16;  // RNE
  return (unsigned short)r;
}

// ---------------- fp32 -> bf16 conversion (vectorized) ----------------
__global__ __launch_bounds__(256) void cvt4_kernel(const float4* __restrict__ in,
                                                   ushort4* __restrict__ out, int n4) {
  int i = blockIdx.x * 256 + threadIdx.x;
  if (i >= n4) return;
  float4 v = in[i];
  ushort4 o;
  o.x = f2b(v.x); o.y = f2b(v.y); o.z = f2b(v.z); o.w = f2b(v.w);
  out[i] = o;
}

// ---------------- GEMM: C[M,N] = A[M,K] * Bw[N,K]^T (bf16 in, K=N=1024) -----
template<int MODE>
__global__ __launch_bounds__(256) void gemm_bt(
    const unsigned short* __restrict__ A,
    const unsigned short* __restrict__ B0,
    const unsigned short* __restrict__ B1,
    const unsigned short* __restrict__ B2,
    unsigned short* __restrict__ O0,
    unsigned short* __restrict__ O1,
    unsigned short* __restrict__ O2,
    float* __restrict__ OF)
{
  const int tid  = threadIdx.x;
  const int lane = tid & 63;
  const int w    = tid >> 6;          // wave 0..3
  const int wm   = w >> 1, wn = w & 1;
  const int r16  = lane & 15, g = lane >> 4;
  const int bm = blockIdx.x, bn = blockIdx.y;

  const unsigned short* Bw = B0;
  unsigned short* Ob = O0;
  if (MODE == 0) {
    if (blockIdx.z == 1)      { Bw = B1; Ob = O1; }
    else if (blockIdx.z == 2) { Bw = B2; Ob = O2; }
  }

  __shared__ unsigned short As[128][40];
  __shared__ unsigned short Bs[128][40];

  f32x4 acc[4][4] = {};
  const int arow = bm * 128;
  const int brow = bn * 128;

  for (int k0 = 0; k0 < 1024; k0 += 32) {
    #pragma unroll
    for (int t = 0; t < 2; ++t) {
      int cc  = tid + t * 256;
      int row = cc >> 2, col = (cc & 3) * 8;
      *(uint4*)(&As[row][col]) = *(const uint4*)(&A [(size_t)(arow + row) * 1024 + k0 + col]);
      *(uint4*)(&Bs[row][col]) = *(const uint4*)(&Bw[(size_t)(brow + row) * 1024 + k0 + col]);
    }
    __syncthreads();
    bf16x8 af[4], bfr[4];
    #pragma unroll
    for (int i = 0; i < 4; ++i)
      af[i]  = *(const bf16x8*)(&As[wm*64 + i*16 + r16][g*8]);
    #pragma unroll
    for (int i = 0; i < 4; ++i)
      bfr[i] = *(const bf16x8*)(&Bs[wn*64 + i*16 + r16][g*8]);
    #pragma unroll
    for (int i = 0; i < 4; ++i)
      #pragma unroll
      for (int j = 0; j < 4; ++j)
        acc[i][j] = __builtin_amdgcn_mfma_f32_16x16x32_bf16(af[i], bfr[j], acc[i][j], 0, 0, 0);
    __syncthreads();
  }

  #pragma unroll
  for (int i = 0; i < 4; ++i) {
    #pragma unroll
    for (int j = 0; j < 4; ++j) {
      #pragma unroll
      for (int r = 0; r < 4; ++r) {
        int m = bm*128 + wm*64 + i*16 + g*4 + r;
        int n = bn*128 + wn*64 + j*16 + r16;
        float v = acc[i][j][r];
        if (MODE == 0) {
          int b = m >> 11, s = m & 2047;
          int h = n >> 6,  hd = n & 63;
          Ob[((((size_t)b*H_ + h)*S_) + s)*HD_ + hd] = f2b(v);
        } else {
          OF[(size_t)m * 1024 + n] = v;
        }
      }
    }
  }
}

// ---------------- V transpose: [bh][2048][64] -> [bh][64][2048] ----------
// 2x2-uint micro-transpose through LDS; conflict-free both sides.
__global__ __launch_bounds__(256) void transpose_v(const unsigned short* __restrict__ in,
                                                   unsigned short* __restrict__ out) {
  __shared__ unsigned int T4[64][33];
  const int t  = threadIdx.x;
  const int bh = blockIdx.y, s0 = blockIdx.x * 64;
  const unsigned int* in4  = (const unsigned int*)(in + (size_t)bh * S_ * HD_);
  unsigned int* out4       = (unsigned int*)(out + (size_t)bh * HD_ * S_);
  #pragma unroll
  for (int rr = 0; rr < 4; ++rr) {
    int bi = t + rr * 256;
    int s2 = bi >> 5, h2 = bi & 31;
    unsigned A  = in4[(size_t)(s0 + 2*s2)     * 32 + h2];
    unsigned Bu = in4[(size_t)(s0 + 2*s2 + 1) * 32 + h2];
    T4[2*h2][s2]     = (A & 0xFFFFu) | (Bu << 16);           // V^T[2h2][2s2..2s2+1]
    T4[2*h2 + 1][s2] = (A >> 16) | (Bu & 0xFFFF0000u);       // V^T[2h2+1][...]
  }
  __syncthreads();
  #pragma unroll
  for (int rr = 0; rr < 2; ++rr) {
    int oi = t + rr * 256;
    int row = oi >> 3, c4 = (oi & 7) * 4;
    uint4 v;
    v.x = T4[row][c4 + 0]; v.y = T4[row][c4 + 1];
    v.z = T4[row][c4 + 2]; v.w = T4[row][c4 + 3];
    *(uint4*)(&out4[(size_t)row * (S_/2) + (s0 >> 1) + c4]) = v;
  }
}

// ---------------- flash attention, causal, block-cooperative -------------
// Q,K: [bh][2048][64]; Vt: [bh][64][2048]. Block = 4 waves, 128 q-rows of one
// head; wave owns 32 q-rows. KV staged in LDS per 64-col step, shared by all
// waves (uniform trip count; ragged edges handled by causal mask).
__global__ __launch_bounds__(256) void attn_fwd(
    const unsigned short* __restrict__ Q,
    const unsigned short* __restrict__ K,
    const unsigned short* __restrict__ Vt,
    unsigned short* __restrict__ C)
{
  const int tid  = threadIdx.x;
  const int lane = tid & 63;
  const int w    = tid >> 6;
  const int r16  = lane & 15, g = lane >> 4;
  const int bh   = blockIdx.y;
  const int bb   = bh >> 4, hh = bh & 15;
  const int q0   = blockIdx.x * 128;
  const int qw   = q0 + w * 32;
  const unsigned short* Qh = Q  + (size_t)bh * S_ * HD_;
  const unsigned short* Kh = K  + (size_t)bh * S_ * HD_;
  const unsigned short* Vh = Vt + (size_t)bh * HD_ * S_;   // [64][2048]

  __shared__ unsigned short Ks[64][72];
  __shared__ unsigned short Vs[64][72];
  __shared__ unsigned short Pl[4][32][72];

  bf16x8 qf[2][2];
  #pragma unroll
  for (int qi = 0; qi < 2; ++qi)
    #pragma unroll
    for (int dh = 0; dh < 2; ++dh)
      qf[qi][dh] = *(const bf16x8*)(&Qh[(size_t)(qw + qi*16 + r16) * HD_ + dh*32 + g*8]);

  f32x4 o[2][4] = {};
  float mrow[2][4], lrow[2][4];
  #pragma unroll
  for (int qi = 0; qi < 2; ++qi)
    #pragma unroll
    for (int r = 0; r < 4; ++r) { mrow[qi][r] = -1e30f; lrow[qi][r] = 0.f; }

  const int nk = (q0 >> 6) + 2;   // KV tiles covering [0, q0+128)
  for (int kt = 0; kt < nk; ++kt) {
    const int kb = kt * 64;
    __syncthreads();
    #pragma unroll
    for (int rr = 0; rr < 2; ++rr) {          // stage K[64][64] and Vt[64][64]
      int idx = tid + rr * 256;
      int row = idx >> 3, col = (idx & 7) * 8;
      *(uint4*)(&Ks[row][col]) = *(const uint4*)(&Kh[(size_t)(kb + row) * HD_ + col]);
      *(uint4*)(&Vs[row][col]) = *(const uint4*)(&Vh[(size_t)row * S_ + kb + col]);
    }
    __syncthreads();

    // ---- QK^T: 16 MFMA ----
    f32x4 sc[2][4];
    #pragma unroll
    for (int c = 0; c < 4; ++c) {
      bf16x8 kf0 = *(const bf16x8*)(&Ks[c*16 + r16][g*8]);
      bf16x8 kf1 = *(const bf16x8*)(&Ks[c*16 + r16][32 + g*8]);
      #pragma unroll
      for (int qi = 0; qi < 2; ++qi) {
        f32x4 s = {};
        s = __builtin_amdgcn_mfma_f32_16x16x32_bf16(qf[qi][0], kf0, s, 0, 0, 0);
        s = __builtin_amdgcn_mfma_f32_16x16x32_bf16(qf[qi][1], kf1, s, 0, 0, 0);
        sc[qi][c] = s;
      }
    }

    // ---- online softmax (lane owns rows g*4+r of each 16-row frag) ----
    #pragma unroll
    for (int qi = 0; qi < 2; ++qi) {
      #pragma unroll
      for (int r = 0; r < 4; ++r) {
        const int qrow = qw + qi*16 + g*4 + r;
        float v[4];
        #pragma unroll
        for (int c = 0; c < 4; ++c) {
          v[c] = sc[qi][c][r] * 0.125f;
          if (kb + c*16 + r16 > qrow) v[c] = -1e30f;
        }
        float t2 = fmaxf(fmaxf(v[0], v[1]), fmaxf(v[2], v[3]));
        #pragma unroll
        for (int off = 1; off < 16; off <<= 1) t2 = fmaxf(t2, __shfl_xor(t2, off));
        float mnew = fmaxf(mrow[qi][r], t2);
        float resc = __expf(mrow[qi][r] - mnew);
        mrow[qi][r] = mnew;
        float p[4], ts = 0.f;
        #pragma unroll
        for (int c = 0; c < 4; ++c) { p[c] = __expf(v[c] - mnew); ts += p[c]; }
        #pragma unroll
        for (int off = 1; off < 16; off <<= 1) ts += __shfl_xor(ts, off);
        lrow[qi][r] = lrow[qi][r] * resc + ts;
        #pragma unroll
        for (int dn = 0; dn < 4; ++dn) o[qi][dn][r] *= resc;
        #pragma unroll
        for (int c = 0; c < 4; ++c)
          Pl[w][qi*16 + g*4 + r][c*16 + r16] = f2b(p[c]);
      }
    }

    // ---- PV: 16 MFMA (wave-private Pl; compiler orders same-wave RAW) ----
    #pragma unroll
    for (int kc = 0; kc < 2; ++kc) {
      bf16x8 pf0 = *(const bf16x8*)(&Pl[w][r16][kc*32 + g*8]);
      bf16x8 pf1 = *(const bf16x8*)(&Pl[w][16 + r16][kc*32 + g*8]);
      #pragma unroll
      for (int dn = 0; dn < 4; ++dn) {
        bf16x8 vf = *(const bf16x8*)(&Vs[dn*16 + r16][kc*32 + g*8]);
        o[0][dn] = __builtin_amdgcn_mfma_f32_16x16x32_bf16(pf0, vf, o[0][dn], 0, 0, 0);
        o[1][dn] = __builtin_amdgcn_mfma_f32_16x16x32_bf16(pf1, vf, o[1][dn], 0, 0, 0);
      }
    }
  }

  // ---- write ctx merged-head layout [b][s][1024] ----
  #pragma unroll
  for (int qi = 0; qi < 2; ++qi)
    #pragma unroll
    for (int dn = 0; dn < 4; ++dn)
      #pragma unroll
      for (int r = 0; r < 4; ++r) {
        int tok = bb * S_ + qw + qi*16 + g*4 + r;
        C[(size_t)tok * D_ + hh*HD_ + dn*16 + r16] = f2b(o[qi][dn][r] / lrow[qi][r]);
      }
}

// ---------------- launch ------------------------------------------------
extern "C" void kernel_launch(void* const* d_in, const int* in_sizes, int n_in,
                              void* d_out, int out_size, void* d_ws, size_t ws_size,
                              hipStream_t stream) {
  const float* x  = (const float*)d_in[0];
  const float* Wq = (const float*)d_in[1];
  const float* Wk = (const float*)d_in[2];
  const float* Wv = (const float*)d_in[3];
  const float* Wo = (const float*)d_in[4];

  char* ws = (char*)d_ws;
  unsigned short* xb  = (unsigned short*)(ws);              // 16 MiB (dead after projections)
  unsigned short* Vtb = (unsigned short*)(ws);              // overlaid on xb: V^T [bh][64][2048]
  unsigned short* Wqb = (unsigned short*)(ws + 16777216);
  unsigned short* Wkb = (unsigned short*)(ws + 18874368);
  unsigned short* Wvb = (unsigned short*)(ws + 20971520);
  unsigned short* Wob = (unsigned short*)(ws + 23068672);
  unsigned short* Qb  = (unsigned short*)(ws + 25165824);   // [b][h][s][hd]
  unsigned short* Kb  = (unsigned short*)(ws + 41943040);
  unsigned short* Vb  = (unsigned short*)(ws + 58720256);
  unsigned short* Cb  = (unsigned short*)(ws + 75497472);   // ctx [b][s][1024]

  cvt4_kernel<<<8192, 256, 0, stream>>>((const float4*)x,  (ushort4*)xb,  2097152);
  cvt4_kernel<<<1024, 256, 0, stream>>>((const float4*)Wq, (ushort4*)Wqb, 262144);
  cvt4_kernel<<<1024, 256, 0, stream>>>((const float4*)Wk, (ushort4*)Wkb, 262144);
  cvt4_kernel<<<1024, 256, 0, stream>>>((const float4*)Wv, (ushort4*)Wvb, 262144);
  cvt4_kernel<<<1024, 256, 0, stream>>>((const float4*)Wo, (ushort4*)Wob, 262144);

  gemm_bt<0><<<dim3(64, 8, 3), 256, 0, stream>>>(xb, Wqb, Wkb, Wvb, Qb, Kb, Vb, nullptr);
  transpose_v<<<dim3(32, 64), 256, 0, stream>>>(Vb, Vtb);   // xb dead from here
  attn_fwd<<<dim3(16, 64), 256, 0, stream>>>(Qb, Kb, Vtb, Cb);
  gemm_bt<1><<<dim3(64, 8, 1), 256, 0, stream>>>(Cb, Wob, nullptr, nullptr,
                                                 nullptr, nullptr, nullptr, (float*)d_out);
}

// Round 3
// 219.857 us; speedup vs baseline: 2.2969x; 1.8091x over previous
//
#include <hip/hip_runtime.h>

// Self-attention: x(4,2048,1024) fp32; W_Q/K/V/O (1024,1024) fp32.
// bf16 MFMA GEMMs + flash attention (swapped-operand softmax, paired q-tiles,
// double-buffered KV staging, XCD-pinned heads).

#define B_  4
#define S_  2048
#define D_  1024
#define H_  16
#define HD_ 64

typedef __attribute__((ext_vector_type(8))) short bf16x8;
typedef __attribute__((ext_vector_type(4))) float f32x4;

__device__ __forceinline__ unsigned short f2b(float f) {
  unsigned u = __builtin_bit_cast(unsigned, f);
  unsigned r = (u + 0x7FFFu + ((u >> 16) & 1u)) >> 16;  // RNE
  return (unsigned short)r;
}

__device__ __forceinline__ unsigned cvtpk(float lo, float hi) {
  unsigned r;
  asm("v_cvt_pk_bf16_f32 %0, %1, %2" : "=v"(r) : "v"(lo), "v"(hi));
  return r;
}

// ---------------- fp32 -> bf16 conversion (vectorized) ----------------
__global__ __launch_bounds__(256) void cvt4_kernel(const float4* __restrict__ in,
                                                   ushort4* __restrict__ out, int n4) {
  int i = blockIdx.x * 256 + threadIdx.x;
  if (i >= n4) return;
  float4 v = in[i];
  ushort4 o;
  o.x = f2b(v.x); o.y = f2b(v.y); o.z = f2b(v.z); o.w = f2b(v.w);
  out[i] = o;
}

// ---------------- GEMM: C[M,N] = A[M,K] * Bw[N,K]^T (bf16 in, K=N=1024) -----
template<int MODE>
__global__ __launch_bounds__(256) void gemm_bt(
    const unsigned short* __restrict__ A,
    const unsigned short* __restrict__ B0,
    const unsigned short* __restrict__ B1,
    const unsigned short* __restrict__ B2,
    unsigned short* __restrict__ O0,
    unsigned short* __restrict__ O1,
    unsigned short* __restrict__ O2,
    float* __restrict__ OF)
{
  const int tid  = threadIdx.x;
  const int lane = tid & 63;
  const int w    = tid >> 6;          // wave 0..3
  const int wm   = w >> 1, wn = w & 1;
  const int r16  = lane & 15, g = lane >> 4;
  const int bm = blockIdx.x, bn = blockIdx.y;

  const unsigned short* Bw = B0;
  unsigned short* Ob = O0;
  if (MODE == 0) {
    if (blockIdx.z == 1)      { Bw = B1; Ob = O1; }
    else if (blockIdx.z == 2) { Bw = B2; Ob = O2; }
  }

  __shared__ unsigned short As[128][40];
  __shared__ unsigned short Bs[128][40];

  f32x4 acc[4][4] = {};
  const int arow = bm * 128;
  const int brow = bn * 128;

  for (int k0 = 0; k0 < 1024; k0 += 32) {
    #pragma unroll
    for (int t = 0; t < 2; ++t) {
      int cc  = tid + t * 256;
      int row = cc >> 2, col = (cc & 3) * 8;
      *(uint4*)(&As[row][col]) = *(const uint4*)(&A [(size_t)(arow + row) * 1024 + k0 + col]);
      *(uint4*)(&Bs[row][col]) = *(const uint4*)(&Bw[(size_t)(brow + row) * 1024 + k0 + col]);
    }
    __syncthreads();
    bf16x8 af[4], bfr[4];
    #pragma unroll
    for (int i = 0; i < 4; ++i)
      af[i]  = *(const bf16x8*)(&As[wm*64 + i*16 + r16][g*8]);
    #pragma unroll
    for (int i = 0; i < 4; ++i)
      bfr[i] = *(const bf16x8*)(&Bs[wn*64 + i*16 + r16][g*8]);
    #pragma unroll
    for (int i = 0; i < 4; ++i)
      #pragma unroll
      for (int j = 0; j < 4; ++j)
        acc[i][j] = __builtin_amdgcn_mfma_f32_16x16x32_bf16(af[i], bfr[j], acc[i][j], 0, 0, 0);
    __syncthreads();
  }

  #pragma unroll
  for (int i = 0; i < 4; ++i) {
    #pragma unroll
    for (int j = 0; j < 4; ++j) {
      #pragma unroll
      for (int r = 0; r < 4; ++r) {
        int m = bm*128 + wm*64 + i*16 + g*4 + r;
        int n = bn*128 + wn*64 + j*16 + r16;
        float v = acc[i][j][r];
        if (MODE == 0) {
          int b = m >> 11, s = m & 2047;
          int h = n >> 6,  hd = n & 63;
          Ob[((((size_t)b*H_ + h)*S_) + s)*HD_ + hd] = f2b(v);
        } else {
          OF[(size_t)m * 1024 + n] = v;
        }
      }
    }
  }
}

// ---------------- V transpose: [bh][2048][64] -> [bh][64][2048] ----------
__global__ __launch_bounds__(256) void transpose_v(const unsigned short* __restrict__ in,
                                                   unsigned short* __restrict__ out) {
  __shared__ unsigned int T4[64][33];
  const int t  = threadIdx.x;
  const int bh = blockIdx.y, s0 = blockIdx.x * 64;
  const unsigned int* in4  = (const unsigned int*)(in + (size_t)bh * S_ * HD_);
  unsigned int* out4       = (unsigned int*)(out + (size_t)bh * HD_ * S_);
  #pragma unroll
  for (int rr = 0; rr < 4; ++rr) {
    int bi = t + rr * 256;
    int s2 = bi >> 5, h2 = bi & 31;
    unsigned A  = in4[(size_t)(s0 + 2*s2)     * 32 + h2];
    unsigned Bu = in4[(size_t)(s0 + 2*s2 + 1) * 32 + h2];
    T4[2*h2][s2]     = (A & 0xFFFFu) | (Bu << 16);
    T4[2*h2 + 1][s2] = (A >> 16) | (Bu & 0xFFFF0000u);
  }
  __syncthreads();
  #pragma unroll
  for (int rr = 0; rr < 2; ++rr) {
    int oi = t + rr * 256;
    int row = oi >> 3, c4 = (oi & 7) * 4;
    uint4 v;
    v.x = T4[row][c4 + 0]; v.y = T4[row][c4 + 1];
    v.z = T4[row][c4 + 2]; v.w = T4[row][c4 + 3];
    *(uint4*)(&out4[(size_t)row * (S_/2) + (s0 >> 1) + c4]) = v;
  }
}

// ---------------- flash attention, causal -------------------------------
// Q,K: [bh][2048][64]; Vt: [bh][64][2048]. 1-D grid of 512 blocks; block
// handles head bh (XCD-pinned) and the q-tile PAIR (px, 15-px) -> uniform
// 36 KV-tiles/block. Swapped-operand MFMA: scores/ctx computed transposed so
// softmax rows are keyed by lane&15 (in-lane max, 2 shfl; lane-partial sums).
__global__ __launch_bounds__(256) void attn_fwd(
    const unsigned short* __restrict__ Q,
    const unsigned short* __restrict__ K,
    const unsigned short* __restrict__ Vt,
    unsigned short* __restrict__ C)
{
  const int tid  = threadIdx.x;
  const int lane = tid & 63;
  const int w    = tid >> 6;
  const int r16  = lane & 15, g = lane >> 4;

  const int l_   = blockIdx.x;
  const int bh   = (l_ & 7) * 8 + ((l_ >> 3) & 7);   // 8 heads per XCD
  const int px   = l_ >> 6;                          // 0..7
  const int bb   = bh >> 4, hh = bh & 15;

  const unsigned short* Qh = Q  + (size_t)bh * S_ * HD_;
  const unsigned short* Kh = K  + (size_t)bh * S_ * HD_;
  const unsigned short* Vh = Vt + (size_t)bh * HD_ * S_;   // [64 hd][2048 k]

  __shared__ unsigned short Ks[64][72];    // [k][d]
  __shared__ unsigned short Vs[64][72];    // [hd][k]
  __shared__ unsigned short Pl[4][32][72]; // per-wave P[q][k]

  const int row0 = tid >> 3, colX = (tid & 7) * 8;  // staging coords (rows 0..31)
  const float kSc = 0.18033688f;                    // 0.125 * log2(e)

  #pragma unroll
  for (int ph = 0; ph < 2; ++ph) {
    const int jt = ph ? (15 - px) : px;
    const int q0 = jt * 128;
    const int qw = q0 + w * 32;
    const int nt = 2 * jt + 2;

    bf16x8 qf[2][2];
    #pragma unroll
    for (int qi = 0; qi < 2; ++qi)
      #pragma unroll
      for (int dh = 0; dh < 2; ++dh)
        qf[qi][dh] = *(const bf16x8*)(&Qh[(size_t)(qw + qi*16 + r16) * HD_ + dh*32 + g*8]);

    f32x4 oT[2][4] = {};          // ctx^T: [qi][dn], q=r16, hd=dn*16+g*4+reg
    float mQ[2] = {-1e30f, -1e30f};
    float lQ[2] = {0.f, 0.f};

    // prefetch tile 0
    uint4 kr0 = *(const uint4*)(&Kh[(size_t)row0        * HD_ + colX]);
    uint4 kr1 = *(const uint4*)(&Kh[(size_t)(row0 + 32) * HD_ + colX]);
    uint4 vr0 = *(const uint4*)(&Vh[(size_t)row0        * S_  + colX]);
    uint4 vr1 = *(const uint4*)(&Vh[(size_t)(row0 + 32) * S_  + colX]);

    for (int kt = 0; kt < nt; ++kt) {
      const int kb = kt * 64;
      __syncthreads();                       // LDS free (prev tile consumed)
      *(uint4*)(&Ks[row0][colX])      = kr0;
      *(uint4*)(&Ks[row0 + 32][colX]) = kr1;
      *(uint4*)(&Vs[row0][colX])      = vr0;
      *(uint4*)(&Vs[row0 + 32][colX]) = vr1;
      __syncthreads();
      if (kt + 1 < nt) {                     // issue next tile (hidden under compute)
        const int nb = kb + 64;
        kr0 = *(const uint4*)(&Kh[(size_t)(nb + row0)      * HD_ + colX]);
        kr1 = *(const uint4*)(&Kh[(size_t)(nb + row0 + 32) * HD_ + colX]);
        vr0 = *(const uint4*)(&Vh[(size_t)row0        * S_ + nb + colX]);
        vr1 = *(const uint4*)(&Vh[(size_t)(row0 + 32) * S_ + nb + colX]);
      }
      if (kb > qw + 31) continue;            // fully-masked tile for this wave

      // ---- S^T = K Q^T : sc[qi][c][r] = S[q=qw+qi*16+r16][k=kb+c*16+g*4+r]
      f32x4 sc[2][4];
      #pragma unroll
      for (int c = 0; c < 4; ++c) {
        bf16x8 kf0 = *(const bf16x8*)(&Ks[c*16 + r16][g*8]);
        bf16x8 kf1 = *(const bf16x8*)(&Ks[c*16 + r16][32 + g*8]);
        #pragma unroll
        for (int qi = 0; qi < 2; ++qi) {
          f32x4 s = {};
          s = __builtin_amdgcn_mfma_f32_16x16x32_bf16(kf0, qf[qi][0], s, 0, 0, 0);
          s = __builtin_amdgcn_mfma_f32_16x16x32_bf16(kf1, qf[qi][1], s, 0, 0, 0);
          sc[qi][c] = s;
        }
      }

      // ---- online softmax (q-row = r16; k spread over g and in-lane) ----
      #pragma unroll
      for (int qi = 0; qi < 2; ++qi) {
        const int qrow = qw + qi*16 + r16;
        const bool needm = (kb + 63 > qw + qi*16);
        float sv[4][4];
        #pragma unroll
        for (int c = 0; c < 4; ++c)
          #pragma unroll
          for (int r = 0; r < 4; ++r) {
            float v = sc[qi][c][r] * kSc;
            if (needm && (kb + c*16 + g*4 + r > qrow)) v = -1e30f;
            sv[c][r] = v;
          }
        float mx = sv[0][0];
        #pragma unroll
        for (int c = 0; c < 4; ++c)
          #pragma unroll
          for (int r = 0; r < 4; ++r) mx = fmaxf(mx, sv[c][r]);
        mx = fmaxf(mx, __shfl_xor(mx, 16));
        mx = fmaxf(mx, __shfl_xor(mx, 32));
        float mnew = fmaxf(mQ[qi], mx);
        float resc = exp2f(mQ[qi] - mnew);
        mQ[qi] = mnew;
        float ps[4][4], ss = 0.f;
        #pragma unroll
        for (int c = 0; c < 4; ++c)
          #pragma unroll
          for (int r = 0; r < 4; ++r) { ps[c][r] = exp2f(sv[c][r] - mnew); ss += ps[c][r]; }
        lQ[qi] = lQ[qi] * resc + ss;
        #pragma unroll
        for (int dn = 0; dn < 4; ++dn)
          #pragma unroll
          for (int r = 0; r < 4; ++r) oT[qi][dn][r] *= resc;
        #pragma unroll
        for (int c = 0; c < 4; ++c) {
          uint2 pw;
          pw.x = cvtpk(ps[c][0], ps[c][1]);
          pw.y = cvtpk(ps[c][2], ps[c][3]);
          *(uint2*)(&Pl[w][qi*16 + r16][c*16 + g*4]) = pw;
        }
      }

      // ---- ctx^T += V^T P^T : oT[qi][dn] (wave-private Pl RAW) ----
      #pragma unroll
      for (int kc = 0; kc < 2; ++kc) {
        bf16x8 pf0 = *(const bf16x8*)(&Pl[w][r16][kc*32 + g*8]);
        bf16x8 pf1 = *(const bf16x8*)(&Pl[w][16 + r16][kc*32 + g*8]);
        #pragma unroll
        for (int dn = 0; dn < 4; ++dn) {
          bf16x8 vf = *(const bf16x8*)(&Vs[dn*16 + r16][kc*32 + g*8]);
          oT[0][dn] = __builtin_amdgcn_mfma_f32_16x16x32_bf16(vf, pf0, oT[0][dn], 0, 0, 0);
          oT[1][dn] = __builtin_amdgcn_mfma_f32_16x16x32_bf16(vf, pf1, oT[1][dn], 0, 0, 0);
        }
      }
    }

    // ---- epilogue: reduce l over g, normalize, packed store ----
    #pragma unroll
    for (int qi = 0; qi < 2; ++qi) {
      float l = lQ[qi];
      l += __shfl_xor(l, 16);
      l += __shfl_xor(l, 32);
      float inv = 1.0f / l;
      int tok = bb * S_ + qw + qi*16 + r16;
      #pragma unroll
      for (int dn = 0; dn < 4; ++dn) {
        uint2 cw;
        cw.x = cvtpk(oT[qi][dn][0] * inv, oT[qi][dn][1] * inv);
        cw.y = cvtpk(oT[qi][dn][2] * inv, oT[qi][dn][3] * inv);
        *(uint2*)(&C[(size_t)tok * D_ + hh*HD_ + dn*16 + g*4]) = cw;
      }
    }
  }
}

// ---------------- launch ------------------------------------------------
extern "C" void kernel_launch(void* const* d_in, const int* in_sizes, int n_in,
                              void* d_out, int out_size, void* d_ws, size_t ws_size,
                              hipStream_t stream) {
  const float* x  = (const float*)d_in[0];
  const float* Wq = (const float*)d_in[1];
  const float* Wk = (const float*)d_in[2];
  const float* Wv = (const float*)d_in[3];
  const float* Wo = (const float*)d_in[4];

  char* ws = (char*)d_ws;
  unsigned short* xb  = (unsigned short*)(ws);              // dead after projections
  unsigned short* Vtb = (unsigned short*)(ws);              // overlaid: V^T [bh][64][2048]
  unsigned short* Wqb = (unsigned short*)(ws + 16777216);
  unsigned short* Wkb = (unsigned short*)(ws + 18874368);
  unsigned short* Wvb = (unsigned short*)(ws + 20971520);
  unsigned short* Wob = (unsigned short*)(ws + 23068672);
  unsigned short* Qb  = (unsigned short*)(ws + 25165824);   // [b][h][s][hd]
  unsigned short* Kb  = (unsigned short*)(ws + 41943040);
  unsigned short* Vb  = (unsigned short*)(ws + 58720256);
  unsigned short* Cb  = (unsigned short*)(ws + 75497472);   // ctx [b][s][1024]

  cvt4_kernel<<<8192, 256, 0, stream>>>((const float4*)x,  (ushort4*)xb,  2097152);
  cvt4_kernel<<<1024, 256, 0, stream>>>((const float4*)Wq, (ushort4*)Wqb, 262144);
  cvt4_kernel<<<1024, 256, 0, stream>>>((const float4*)Wk, (ushort4*)Wkb, 262144);
  cvt4_kernel<<<1024, 256, 0, stream>>>((const float4*)Wv, (ushort4*)Wvb, 262144);
  cvt4_kernel<<<1024, 256, 0, stream>>>((const float4*)Wo, (ushort4*)Wob, 262144);

  gemm_bt<0><<<dim3(64, 8, 3), 256, 0, stream>>>(xb, Wqb, Wkb, Wvb, Qb, Kb, Vb, nullptr);
  transpose_v<<<dim3(32, 64), 256, 0, stream>>>(Vb, Vtb);
  attn_fwd<<<512, 256, 0, stream>>>(Qb, Kb, Vtb, Cb);
  gemm_bt<1><<<dim3(64, 8, 1), 256, 0, stream>>>(Cb, Wob, nullptr, nullptr,
                                                 nullptr, nullptr, nullptr, (float*)d_out);
}